// Round 6
// baseline (297.447 us; speedup 1.0000x reference)
//
#include <hip/hip_runtime.h>
#include <hip/hip_bf16.h>

typedef _Float16 f16;
typedef _Float16 half8 __attribute__((ext_vector_type(8)));
typedef _Float16 half4 __attribute__((ext_vector_type(4)));
typedef float f32x4 __attribute__((ext_vector_type(4)));
typedef unsigned short u16;
typedef unsigned int u32;

#define AS_GLOBAL __attribute__((address_space(1)))
#define AS_LDS    __attribute__((address_space(3)))

static __device__ __forceinline__ f32x4 mfma_k32(half8 a, half8 b, f32x4 c) {
  return __builtin_amdgcn_mfma_f32_16x16x32_f16(a, b, c, 0, 0, 0);
}

// async global->LDS, 16B per lane; LDS dest is wave-uniform base, HW adds lane*16
static __device__ __forceinline__ void glds16(const void* g, void* l) {
  __builtin_amdgcn_global_load_lds((const AS_GLOBAL u32*)(unsigned long long)g,
                                   (AS_LDS u32*)l, 16, 0, 0);
}

// ---------------- fused f32 -> f16 convert for all three inputs ----------------
// blocks [0,6144): x (12582912 elems); [6144,7008): qkv_w (1769472); [7008,7296): proj_w (589824)
__global__ __launch_bounds__(256) void cvt_all_kernel(const float* __restrict__ x,
                                                      const float* __restrict__ w1,
                                                      const float* __restrict__ w2,
                                                      f16* __restrict__ xo,
                                                      f16* __restrict__ w1o,
                                                      f16* __restrict__ w2o) {
  const int bx = blockIdx.x;
  const float* src; f16* dst; long base;
  if (bx < 6144)      { src = x;  dst = xo;  base = (long)bx * 2048; }
  else if (bx < 7008) { src = w1; dst = w1o; base = (long)(bx - 6144) * 2048; }
  else                { src = w2; dst = w2o; base = (long)(bx - 7008) * 2048; }
  const long i = base + (long)threadIdx.x * 8;
  const float4 a = *(const float4*)(src + i);
  const float4 b = *(const float4*)(src + i + 4);
  union { uint4 v; f16 h[8]; } o;
  o.h[0] = (f16)a.x; o.h[1] = (f16)a.y; o.h[2] = (f16)a.z; o.h[3] = (f16)a.w;
  o.h[4] = (f16)b.x; o.h[5] = (f16)b.y; o.h[6] = (f16)b.z; o.h[7] = (f16)b.w;
  *(uint4*)(dst + i) = o.v;
}

// ======== 128x128 GEMM core, 4 waves, BK=32, TRIPLE-buffered (48 KB LDS) ========
// C = A(MxK).B(NxK)^T. Pipeline: stage tile t+2 right after the tile-t boundary
// barrier; ONE raw s_barrier per K-tile; counted s_waitcnt vmcnt(4) (tile t+1's
// 4 glds stay in flight across the barrier -- T4). T2 swizzle both-sides:
// LDS linear (glds16 requirement), global source col granule pre-XORed with
// (row mod 16)>>1 & 3, ds_read applies the same XOR -> bank-conflict-free
// (verified round 4: SQ_LDS_BANK_CONFLICT 7.08M -> 0).
static __device__ __forceinline__ void gemm128p(const f16* __restrict__ A, const f16* __restrict__ B,
                                                const int K, const long m0, const long n0,
                                                f16* As, f16* Bs, f32x4 acc[4][4]) {
  const int tid = threadIdx.x;
  const int lane = tid & 63, w = tid >> 6;
  const int l15 = lane & 15, qd = lane >> 4;
  const int wr = w >> 1, wc = w & 1;
  const int srow = w * 16 + (lane >> 2);
  const int sg   = ((lane & 3) ^ ((lane >> 3) & 3)) * 8;   // inverse-swizzled source col
  const f16* gA0 = A + (m0 + srow) * (long)K + sg;
  const f16* gA1 = gA0 + 64 * (long)K;
  const f16* gB0 = B + (n0 + srow) * (long)K + sg;
  const f16* gB1 = gB0 + 64 * (long)K;
  f16* lA = As + w * 512;   // + buf*4096 + call*2048 (f16 units); glds adds lane*16B
  f16* lB = Bs + w * 512;
  const int rg   = (qd ^ ((l15 >> 1) & 3)) * 8;            // swizzled k-offset on read
  const int arow = (wr * 64 + l15) * 32;
  const int brow = (wc * 64 + l15) * 32;
  const int nT = K >> 5;

#define STAGE(t) { const long ko = (long)(t) * 32;                         \
    f16* dA = lA + ((t) % 3) * 4096; f16* dB = lB + ((t) % 3) * 4096;      \
    glds16(gA0 + ko, dA); glds16(gA1 + ko, dA + 2048);                     \
    glds16(gB0 + ko, dB); glds16(gB1 + ko, dB + 2048); }

  STAGE(0); STAGE(1);
  asm volatile("s_waitcnt vmcnt(4)" ::: "memory");
  __builtin_amdgcn_sched_barrier(0);
  __builtin_amdgcn_s_barrier();
  __builtin_amdgcn_sched_barrier(0);
#pragma unroll
  for (int t = 0; t < nT; ++t) {
    if (t + 2 < nT) STAGE(t + 2);                // earliest issue; lands 2 tiles later
    const f16* cA = As + (t % 3) * 4096;
    const f16* cB = Bs + (t % 3) * 4096;
    half8 a0[2], a1[2], b0[2], b1[2];
    // phase 0: (mh0, nh0)
    a0[0] = *(const half8*)(cA + arow + rg);
    a0[1] = *(const half8*)(cA + arow + 512 + rg);
    b0[0] = *(const half8*)(cB + brow + rg);
    b0[1] = *(const half8*)(cB + brow + 512 + rg);
    __builtin_amdgcn_s_setprio(1);
    acc[0][0] = mfma_k32(a0[0], b0[0], acc[0][0]);
    acc[0][1] = mfma_k32(a0[0], b0[1], acc[0][1]);
    acc[1][0] = mfma_k32(a0[1], b0[0], acc[1][0]);
    acc[1][1] = mfma_k32(a0[1], b0[1], acc[1][1]);
    __builtin_amdgcn_s_setprio(0);
    // phase 1: (mh0, nh1)
    b1[0] = *(const half8*)(cB + brow + 1024 + rg);
    b1[1] = *(const half8*)(cB + brow + 1536 + rg);
    __builtin_amdgcn_s_setprio(1);
    acc[0][2] = mfma_k32(a0[0], b1[0], acc[0][2]);
    acc[0][3] = mfma_k32(a0[0], b1[1], acc[0][3]);
    acc[1][2] = mfma_k32(a0[1], b1[0], acc[1][2]);
    acc[1][3] = mfma_k32(a0[1], b1[1], acc[1][3]);
    __builtin_amdgcn_s_setprio(0);
    // phase 2: (mh1, nh1)
    a1[0] = *(const half8*)(cA + arow + 1024 + rg);
    a1[1] = *(const half8*)(cA + arow + 1536 + rg);
    __builtin_amdgcn_s_setprio(1);
    acc[2][2] = mfma_k32(a1[0], b1[0], acc[2][2]);
    acc[2][3] = mfma_k32(a1[0], b1[1], acc[2][3]);
    acc[3][2] = mfma_k32(a1[1], b1[0], acc[3][2]);
    acc[3][3] = mfma_k32(a1[1], b1[1], acc[3][3]);
    // phase 3: (mh1, nh0) -- operands all held in regs
    acc[2][0] = mfma_k32(a1[0], b0[0], acc[2][0]);
    acc[2][1] = mfma_k32(a1[0], b0[1], acc[2][1]);
    acc[3][0] = mfma_k32(a1[1], b0[0], acc[3][0]);
    acc[3][1] = mfma_k32(a1[1], b0[1], acc[3][1]);
    __builtin_amdgcn_s_setprio(0);
    if (t < nT - 1) {
      if (t == nT - 2) { asm volatile("s_waitcnt vmcnt(0)" ::: "memory"); }
      else             { asm volatile("s_waitcnt vmcnt(4)" ::: "memory"); }
      __builtin_amdgcn_sched_barrier(0);
      __builtin_amdgcn_s_barrier();
      __builtin_amdgcn_sched_barrier(0);
    }
  }
#undef STAGE
}

// ---------------- QKV GEMM + fused bias + 2D-RoPE + scatter into (B,H,N,64) ----------------
// Epilogue reverted to the round-4 version (102 us, WRITE_SIZE 137MB): full-wave
// scalar f16 stores + per-element sincos. (Round-5 table+paired-store variant
// regressed: +20% HBM writes from exec-masked stores; VALU was not the bottleneck.)
__global__ __launch_bounds__(256) void qkv_kernel(const f16* __restrict__ X, const f16* __restrict__ W,
                                                  const float* __restrict__ bias,
                                                  f16* __restrict__ Qf, f16* __restrict__ Kf,
                                                  f16* __restrict__ Vf) {
  __shared__ __align__(16) f16 As[12288];   // 3 buf x 128 x 32
  __shared__ __align__(16) f16 Bs[12288];
  f32x4 acc[4][4];
#pragma unroll
  for (int i = 0; i < 4; ++i)
#pragma unroll
    for (int j = 0; j < 4; ++j) acc[i][j] = (f32x4){0.f, 0.f, 0.f, 0.f};
  const long m0 = (long)blockIdx.x * 128;
  const long n0 = (long)blockIdx.y * 128;
  gemm128p(X, W, 768, m0, n0, As, Bs, acc);

  const int tid = threadIdx.x, lane = tid & 63, w = tid >> 6;
  const int l15 = lane & 15, qd = lane >> 4;
  const int wr = w >> 1, wc = w & 1;
  const int bb = (int)(m0 >> 10);               // batch (uniform per block)
  const int slot = (int)(n0 >> 6) + wc;         // 0..35 (uniform per wave)
  const int which = slot / 12, h = slot % 12;
  f16* dst0 = (which == 0) ? Qf : (which == 1) ? Kf : Vf;
  f16* dstbh = dst0 + ((long)(bb * 12 + h)) * 1024 * 64;
  const bool doRope = (which != 2);
  const bool isQ = (which == 0);
  const bool odd = (l15 & 1);
#pragma unroll
  for (int j = 0; j < 4; ++j) {
    const int d = 16 * j + l15;
    const int p = d >> 1;                        // pair index 0..31
    const float fr = exp2f(-0.8304820237218405f * (float)(p & 15)); // 10000^(-(p%16)/16)
    const bool useY = (p < 16);
    const float bv = bias[n0 + 64 * wc + d];
#pragma unroll
    for (int i = 0; i < 4; ++i) {
      const int nbase = (int)(m0 & 1023) + 64 * wr + 16 * i + qd * 4;
#pragma unroll
      for (int r = 0; r < 4; ++r) {
        const int n = nbase + r;
        float v = acc[i][j][r] + bv;
        if (doRope) {
          const float pv = __shfl_xor(v, 1, 64);   // partner element (d^1)
          const float pos = useY ? (float)(n >> 5) : (float)(n & 31);
          float sn, cn;
          __sincosf(pos * fr, &sn, &cn);
          float res = odd ? (pv * sn + v * cn) : (v * cn - pv * sn);
          if (isQ) res *= 0.18033688011112042f;    // attn scale * log2(e)
          v = res;
        }
        dstbh[(long)n * 64 + d] = (f16)v;
      }
    }
  }
}

// ---------------- flash attention: double-buffered K/V LDS, ONE barrier per kt ----------------
// Per iteration: write tile kt+1 into buf^1 (regs loaded a full iter earlier -> HBM
// latency hidden), issue tile kt+2's global loads, compute tile kt from buf, then a
// single __syncthreads covers both "buf^1 writes visible" and "buf reads complete".
// Halves the barrier count vs the 2-barrier version (32 -> 16 convoys).
__global__ __launch_bounds__(256) void attn_kernel(const f16* __restrict__ Qf, const f16* __restrict__ Kf,
                                                   const f16* __restrict__ Vf, f16* __restrict__ Aout) {
  const int lin = (int)blockIdx.x + ((int)blockIdx.y << 3);   // 0..1535
  const int xcd = lin & 7, idx = lin >> 3;                    // idx 0..191
  const int bh = xcd * 24 + (idx >> 3);                       // bijective remap
  const int qt = idx & 7;
  const int b = bh / 12, h = bh % 12;
  const int tid = threadIdx.x;
  const int lane = tid & 63, w = tid >> 6;
  const int l15 = lane & 15, qd = lane >> 4;

  __shared__ __align__(16) f16 Ks[2][64][72];   // [buf][key][d], rows padded to 72
  __shared__ __align__(16) f16 Vts[2][64][72];  // [buf][d][key] (transposed)
  __shared__ float wsum[128];

  const f16* Qg = Qf + ((long)bh * 1024 + qt * 128) * 64;
  const f16* Kg = Kf + (long)bh * 1024 * 64;
  const f16* Vg = Vf + (long)bh * 1024 * 64;

  half8 qb[2][2];
#pragma unroll
  for (int g = 0; g < 2; ++g)
#pragma unroll
    for (int dc = 0; dc < 2; ++dc)
      qb[g][dc] = *(const half8*)(Qg + (w * 32 + g * 16 + l15) * 64 + dc * 32 + qd * 8);

  float lsum[2] = {0.f, 0.f};
  f32x4 O[2][4];
#pragma unroll
  for (int g = 0; g < 2; ++g)
#pragma unroll
    for (int nt = 0; nt < 4; ++nt) O[g][nt] = (f32x4){0.f, 0.f, 0.f, 0.f};

  const int srow = tid >> 2, sch = (tid & 3) * 16;
  const f16* kgb = Kg + (long)srow * 64 + sch;
  const int sk0 = (tid & 31) * 2, scd = tid >> 5;
  const f16* vgb = Vg + (long)sk0 * 64 + scd * 8;
  uint4 kr0, kr1, vr0, vr1;

  auto writeKV = [&](int buf) {
    *(uint4*)(&Ks[buf][srow][sch])     = kr0;
    *(uint4*)(&Ks[buf][srow][sch + 8]) = kr1;
    union { uint4 u; f16 hh[8]; } ua, ub;
    ua.u = vr0; ub.u = vr1;
#pragma unroll
    for (int i2 = 0; i2 < 8; ++i2) {
      union { u32 u; f16 hh[2]; } t2;
      t2.hh[0] = ua.hh[i2]; t2.hh[1] = ub.hh[i2];
      *(u32*)(&Vts[buf][scd * 8 + i2][sk0]) = t2.u;
    }
  };

  // prologue: tile 0 -> buf0; issue tile 1's loads
  kr0 = *(const uint4*)(kgb);
  kr1 = *(const uint4*)(kgb + 8);
  vr0 = *(const uint4*)(vgb);
  vr1 = *(const uint4*)(vgb + 64);
  writeKV(0);
  kr0 = *(const uint4*)(kgb + 4096);
  kr1 = *(const uint4*)(kgb + 4096 + 8);
  vr0 = *(const uint4*)(vgb + 4096);
  vr1 = *(const uint4*)(vgb + 4096 + 64);
  __syncthreads();

  for (int kt = 0; kt < 16; ++kt) {
    const int cur = kt & 1;
    // write tile kt+1 into the other buffer (safe: everyone finished reading it
    // as tile kt-1 before the previous barrier)
    if (kt < 15) writeKV(cur ^ 1);
    // issue tile kt+2's global loads (regs free: consumed by the writes above)
    if (kt < 14) {
      const f16* kp = kgb + (kt + 2) * 4096;
      kr0 = *(const uint4*)(kp);
      kr1 = *(const uint4*)(kp + 8);
      const f16* vp = vgb + (kt + 2) * 4096;
      vr0 = *(const uint4*)(vp);
      vr1 = *(const uint4*)(vp + 64);
    }

    // S^T = K . Q^T  (x32 MFMAs; A=K from LDS, B=Q regs)
    f32x4 S[2][4];
#pragma unroll
    for (int kb = 0; kb < 4; ++kb) {
      const half8 ka0 = *(const half8*)(&Ks[cur][kb * 16 + l15][qd * 8]);
      const half8 ka1 = *(const half8*)(&Ks[cur][kb * 16 + l15][32 + qd * 8]);
#pragma unroll
      for (int g = 0; g < 2; ++g) {
        f32x4 z = (f32x4){0.f, 0.f, 0.f, 0.f};
        z = mfma_k32(ka0, qb[g][0], z);
        z = mfma_k32(ka1, qb[g][1], z);
        S[g][kb] = z;
      }
    }

    // P = exp2(S^T) packed straight into x32 PV A-fragments
    half8 pa8[2][2];
#pragma unroll
    for (int g = 0; g < 2; ++g)
#pragma unroll
      for (int c = 0; c < 2; ++c) {
        const f32x4 s0 = S[g][2 * c], s1 = S[g][2 * c + 1];
        const float p0 = __builtin_amdgcn_exp2f(s0[0]);
        const float p1 = __builtin_amdgcn_exp2f(s0[1]);
        const float p2 = __builtin_amdgcn_exp2f(s0[2]);
        const float p3 = __builtin_amdgcn_exp2f(s0[3]);
        const float p4 = __builtin_amdgcn_exp2f(s1[0]);
        const float p5 = __builtin_amdgcn_exp2f(s1[1]);
        const float p6 = __builtin_amdgcn_exp2f(s1[2]);
        const float p7 = __builtin_amdgcn_exp2f(s1[3]);
        lsum[g] += ((p0 + p1) + (p2 + p3)) + ((p4 + p5) + (p6 + p7));
        half8 pk;
        pk[0] = (f16)p0; pk[1] = (f16)p1; pk[2] = (f16)p2; pk[3] = (f16)p3;
        pk[4] = (f16)p4; pk[5] = (f16)p5; pk[6] = (f16)p6; pk[7] = (f16)p7;
        pa8[g][c] = pk;
      }

    // O += P . V  (x32 MFMAs; B reads V^T at the lane's own keys)
#pragma unroll
    for (int nt = 0; nt < 4; ++nt) {
      half8 vv[2];
#pragma unroll
      for (int c = 0; c < 2; ++c) {
        const half4 v0 = *(const half4*)(&Vts[cur][nt * 16 + l15][c * 32 + qd * 4]);
        const half4 v1 = *(const half4*)(&Vts[cur][nt * 16 + l15][c * 32 + 16 + qd * 4]);
        vv[c] = __builtin_shufflevector(v0, v1, 0, 1, 2, 3, 4, 5, 6, 7);
      }
#pragma unroll
      for (int g = 0; g < 2; ++g) {
        O[g][nt] = mfma_k32(pa8[g][0], vv[0], O[g][nt]);
        O[g][nt] = mfma_k32(pa8[g][1], vv[1], O[g][nt]);
      }
    }
    __syncthreads();   // buf^1 writes visible AND buf reads complete
  }

#pragma unroll
  for (int g = 0; g < 2; ++g) {
    float s = lsum[g];
    s += __shfl_xor(s, 16, 64);
    s += __shfl_xor(s, 32, 64);
    if (lane < 16) wsum[w * 32 + g * 16 + lane] = s;
  }
  __syncthreads();
  float inv[2][4];
#pragma unroll
  for (int g = 0; g < 2; ++g)
#pragma unroll
    for (int r = 0; r < 4; ++r)
      inv[g][r] = 1.f / wsum[w * 32 + g * 16 + qd * 4 + r];
#pragma unroll
  for (int g = 0; g < 2; ++g)
#pragma unroll
    for (int r = 0; r < 4; ++r) {
      const int n = qt * 128 + w * 32 + g * 16 + qd * 4 + r;
      f16* dst = Aout + ((long)b * 1024 + n) * 768 + h * 64;
#pragma unroll
      for (int nt = 0; nt < 4; ++nt)
        dst[nt * 16 + l15] = (f16)(O[g][nt][r] * inv[g][r]);
    }
}

// ---------------- proj GEMM + bias -> f32 out ----------------
__global__ __launch_bounds__(256) void proj_kernel(const f16* __restrict__ A, const f16* __restrict__ W,
                                                   const float* __restrict__ bias, float* __restrict__ out) {
  __shared__ __align__(16) f16 As[12288];   // 3 buf x 128 x 32
  __shared__ __align__(16) f16 Bs[12288];
  f32x4 acc[4][4];
#pragma unroll
  for (int i = 0; i < 4; ++i)
#pragma unroll
    for (int j = 0; j < 4; ++j) acc[i][j] = (f32x4){0.f, 0.f, 0.f, 0.f};
  const long m0 = (long)blockIdx.x * 128;
  const long n0 = (long)blockIdx.y * 128;
  gemm128p(A, W, 768, m0, n0, As, Bs, acc);

  const int tid = threadIdx.x, lane = tid & 63, w = tid >> 6;
  const int l15 = lane & 15, qd = lane >> 4;
  const int wr = w >> 1, wc = w & 1;
#pragma unroll
  for (int j = 0; j < 4; ++j) {
    const int col = (int)n0 + 64 * wc + 16 * j + l15;
    const float bv = bias[col];
#pragma unroll
    for (int i = 0; i < 4; ++i) {
      const long m = m0 + 64 * wr + 16 * i + qd * 4;
#pragma unroll
      for (int r = 0; r < 4; ++r)
        out[(m + r) * 768 + col] = acc[i][j][r] + bv;
    }
  }
}

extern "C" void kernel_launch(void* const* d_in, const int* in_sizes, int n_in,
                              void* d_out, int out_size, void* d_ws, size_t ws_size,
                              hipStream_t stream) {
  const float* x_f    = (const float*)d_in[0];
  const float* qkvw_f = (const float*)d_in[1];
  const float* qkvb_f = (const float*)d_in[2];
  const float* projw_f= (const float*)d_in[3];
  const float* projb_f= (const float*)d_in[4];
  // d_in[5], d_in[6]: height/width = 32 (hardcoded)

  char* ws = (char*)d_ws;
  f16* xh   = (f16*)(ws + 0);           // 16384*768*2  = 25,165,824
  f16* wqh  = (f16*)(ws + 25165824);    // 2304*768*2   =  3,538,944
  f16* wph  = (f16*)(ws + 28704768);    //  768*768*2   =  1,179,648
  f16* Qf   = (f16*)(ws + 29884416);    // 192*1024*64*2 = 25,165,824
  f16* Kf   = (f16*)(ws + 55050240);
  f16* Vf   = (f16*)(ws + 80216064);    // total 105,381,888 B
  f16* Aout = (f16*)(ws + 0);           // aliases xh (dead after qkv_kernel)

  cvt_all_kernel<<<7296, 256, 0, stream>>>(x_f, qkvw_f, projw_f, xh, wqh, wph);
  qkv_kernel<<<dim3(128, 18), 256, 0, stream>>>(xh, wqh, qkvb_f, Qf, Kf, Vf);
  attn_kernel<<<dim3(8, 192), 256, 0, stream>>>(Qf, Kf, Vf, Aout);
  proj_kernel<<<dim3(128, 6), 256, 0, stream>>>(Aout, wph, projb_f, (float*)d_out);
}

// Round 7
// 291.071 us; speedup vs baseline: 1.0219x; 1.0219x over previous
//
#include <hip/hip_runtime.h>
#include <hip/hip_bf16.h>

typedef _Float16 f16;
typedef _Float16 half8 __attribute__((ext_vector_type(8)));
typedef _Float16 half4 __attribute__((ext_vector_type(4)));
typedef float f32x4 __attribute__((ext_vector_type(4)));
typedef unsigned short u16;
typedef unsigned int u32;

#define AS_GLOBAL __attribute__((address_space(1)))
#define AS_LDS    __attribute__((address_space(3)))

static __device__ __forceinline__ f32x4 mfma_k32(half8 a, half8 b, f32x4 c) {
  return __builtin_amdgcn_mfma_f32_16x16x32_f16(a, b, c, 0, 0, 0);
}

// async global->LDS, 16B per lane; LDS dest is wave-uniform base, HW adds lane*16
static __device__ __forceinline__ void glds16(const void* g, void* l) {
  __builtin_amdgcn_global_load_lds((const AS_GLOBAL u32*)(unsigned long long)g,
                                   (AS_LDS u32*)l, 16, 0, 0);
}

// ---------------- fused f32 -> f16 convert for all three inputs ----------------
// blocks [0,6144): x (12582912 elems); [6144,7008): qkv_w (1769472); [7008,7296): proj_w (589824)
__global__ __launch_bounds__(256) void cvt_all_kernel(const float* __restrict__ x,
                                                      const float* __restrict__ w1,
                                                      const float* __restrict__ w2,
                                                      f16* __restrict__ xo,
                                                      f16* __restrict__ w1o,
                                                      f16* __restrict__ w2o) {
  const int bx = blockIdx.x;
  const float* src; f16* dst; long base;
  if (bx < 6144)      { src = x;  dst = xo;  base = (long)bx * 2048; }
  else if (bx < 7008) { src = w1; dst = w1o; base = (long)(bx - 6144) * 2048; }
  else                { src = w2; dst = w2o; base = (long)(bx - 7008) * 2048; }
  const long i = base + (long)threadIdx.x * 8;
  const float4 a = *(const float4*)(src + i);
  const float4 b = *(const float4*)(src + i + 4);
  union { uint4 v; f16 h[8]; } o;
  o.h[0] = (f16)a.x; o.h[1] = (f16)a.y; o.h[2] = (f16)a.z; o.h[3] = (f16)a.w;
  o.h[4] = (f16)b.x; o.h[5] = (f16)b.y; o.h[6] = (f16)b.z; o.h[7] = (f16)b.w;
  *(uint4*)(dst + i) = o.v;
}

// ======== 128x128 GEMM core, 4 waves, BK=32, TRIPLE-buffered (48 KB LDS) ========
// C = A(MxK).B(NxK)^T. Pipeline: stage tile t+2 right after the tile-t boundary
// barrier; ONE raw s_barrier per K-tile; counted s_waitcnt vmcnt(4) (tile t+1's
// 4 glds stay in flight across the barrier -- T4). T2 swizzle both-sides:
// LDS linear (glds16 requirement), global source col granule pre-XORed with
// (row mod 16)>>1 & 3, ds_read applies the same XOR -> bank-conflict-free
// (verified round 4: SQ_LDS_BANK_CONFLICT 7.08M -> 0).
static __device__ __forceinline__ void gemm128p(const f16* __restrict__ A, const f16* __restrict__ B,
                                                const int K, const long m0, const long n0,
                                                f16* As, f16* Bs, f32x4 acc[4][4]) {
  const int tid = threadIdx.x;
  const int lane = tid & 63, w = tid >> 6;
  const int l15 = lane & 15, qd = lane >> 4;
  const int wr = w >> 1, wc = w & 1;
  const int srow = w * 16 + (lane >> 2);
  const int sg   = ((lane & 3) ^ ((lane >> 3) & 3)) * 8;   // inverse-swizzled source col
  const f16* gA0 = A + (m0 + srow) * (long)K + sg;
  const f16* gA1 = gA0 + 64 * (long)K;
  const f16* gB0 = B + (n0 + srow) * (long)K + sg;
  const f16* gB1 = gB0 + 64 * (long)K;
  f16* lA = As + w * 512;   // + buf*4096 + call*2048 (f16 units); glds adds lane*16B
  f16* lB = Bs + w * 512;
  const int rg   = (qd ^ ((l15 >> 1) & 3)) * 8;            // swizzled k-offset on read
  const int arow = (wr * 64 + l15) * 32;
  const int brow = (wc * 64 + l15) * 32;
  const int nT = K >> 5;

#define STAGE(t) { const long ko = (long)(t) * 32;                         \
    f16* dA = lA + ((t) % 3) * 4096; f16* dB = lB + ((t) % 3) * 4096;      \
    glds16(gA0 + ko, dA); glds16(gA1 + ko, dA + 2048);                     \
    glds16(gB0 + ko, dB); glds16(gB1 + ko, dB + 2048); }

  STAGE(0); STAGE(1);
  asm volatile("s_waitcnt vmcnt(4)" ::: "memory");
  __builtin_amdgcn_sched_barrier(0);
  __builtin_amdgcn_s_barrier();
  __builtin_amdgcn_sched_barrier(0);
#pragma unroll
  for (int t = 0; t < nT; ++t) {
    if (t + 2 < nT) STAGE(t + 2);                // earliest issue; lands 2 tiles later
    const f16* cA = As + (t % 3) * 4096;
    const f16* cB = Bs + (t % 3) * 4096;
    half8 a0[2], a1[2], b0[2], b1[2];
    // phase 0: (mh0, nh0)
    a0[0] = *(const half8*)(cA + arow + rg);
    a0[1] = *(const half8*)(cA + arow + 512 + rg);
    b0[0] = *(const half8*)(cB + brow + rg);
    b0[1] = *(const half8*)(cB + brow + 512 + rg);
    __builtin_amdgcn_s_setprio(1);
    acc[0][0] = mfma_k32(a0[0], b0[0], acc[0][0]);
    acc[0][1] = mfma_k32(a0[0], b0[1], acc[0][1]);
    acc[1][0] = mfma_k32(a0[1], b0[0], acc[1][0]);
    acc[1][1] = mfma_k32(a0[1], b0[1], acc[1][1]);
    __builtin_amdgcn_s_setprio(0);
    // phase 1: (mh0, nh1)
    b1[0] = *(const half8*)(cB + brow + 1024 + rg);
    b1[1] = *(const half8*)(cB + brow + 1536 + rg);
    __builtin_amdgcn_s_setprio(1);
    acc[0][2] = mfma_k32(a0[0], b1[0], acc[0][2]);
    acc[0][3] = mfma_k32(a0[0], b1[1], acc[0][3]);
    acc[1][2] = mfma_k32(a0[1], b1[0], acc[1][2]);
    acc[1][3] = mfma_k32(a0[1], b1[1], acc[1][3]);
    __builtin_amdgcn_s_setprio(0);
    // phase 2: (mh1, nh1)
    a1[0] = *(const half8*)(cA + arow + 1024 + rg);
    a1[1] = *(const half8*)(cA + arow + 1536 + rg);
    __builtin_amdgcn_s_setprio(1);
    acc[2][2] = mfma_k32(a1[0], b1[0], acc[2][2]);
    acc[2][3] = mfma_k32(a1[0], b1[1], acc[2][3]);
    acc[3][2] = mfma_k32(a1[1], b1[0], acc[3][2]);
    acc[3][3] = mfma_k32(a1[1], b1[1], acc[3][3]);
    // phase 3: (mh1, nh0) -- operands all held in regs
    acc[2][0] = mfma_k32(a1[0], b0[0], acc[2][0]);
    acc[2][1] = mfma_k32(a1[0], b0[1], acc[2][1]);
    acc[3][0] = mfma_k32(a1[1], b0[0], acc[3][0]);
    acc[3][1] = mfma_k32(a1[1], b0[1], acc[3][1]);
    __builtin_amdgcn_s_setprio(0);
    if (t < nT - 1) {
      if (t == nT - 2) { asm volatile("s_waitcnt vmcnt(0)" ::: "memory"); }
      else             { asm volatile("s_waitcnt vmcnt(4)" ::: "memory"); }
      __builtin_amdgcn_sched_barrier(0);
      __builtin_amdgcn_s_barrier();
      __builtin_amdgcn_sched_barrier(0);
    }
  }
#undef STAGE
}

// ---------------- QKV GEMM + fused bias + 2D-RoPE + coalesced scatter ----------------
// RoPE math identical to the verified round-4 epilogue. NEW: stores go through LDS
// (reusing the GEMM staging buffer, dead after the K-loop). Each wave's output tile
// (64 rows x one head's full 64-d slab) is a CONTIGUOUS 8KB region of Qf/Kf/Vf, so
// the read-back does 8x 16B-per-lane stores (1KB/instr) instead of 64 scalar 2B
// stores at 32B/64B-sector granularity (which caused 1.8x WRITE_SIZE amplification,
// 137MB vs 75.5MB ideal, measured rounds 4-6). LDS stride 76 f16: qd*4 rows ->
// banks {0,24,16,8}, conflict-free writes.
__global__ __launch_bounds__(256) void qkv_kernel(const f16* __restrict__ X, const f16* __restrict__ W,
                                                  const float* __restrict__ bias,
                                                  f16* __restrict__ Qf, f16* __restrict__ Kf,
                                                  f16* __restrict__ Vf) {
  __shared__ __align__(16) f16 smem[24576];   // GEMM: As|Bs (2x 12288); epi: 4x 64x76
  f16* As = smem;
  f16* Bs = smem + 12288;
  f32x4 acc[4][4];
#pragma unroll
  for (int i = 0; i < 4; ++i)
#pragma unroll
    for (int j = 0; j < 4; ++j) acc[i][j] = (f32x4){0.f, 0.f, 0.f, 0.f};
  const long m0 = (long)blockIdx.x * 128;
  const long n0 = (long)blockIdx.y * 128;
  gemm128p(X, W, 768, m0, n0, As, Bs, acc);

  const int tid = threadIdx.x, lane = tid & 63, w = tid >> 6;
  const int l15 = lane & 15, qd = lane >> 4;
  const int wr = w >> 1, wc = w & 1;
  const int bb = (int)(m0 >> 10);               // batch (uniform per block)
  const int slot = (int)(n0 >> 6) + wc;         // 0..35 (uniform per wave)
  const int which = slot / 12, h = slot % 12;
  f16* dst0 = (which == 0) ? Qf : (which == 1) ? Kf : Vf;
  f16* dstbh = dst0 + ((long)(bb * 12 + h)) * 1024 * 64;
  const bool doRope = (which != 2);
  const bool isQ = (which == 0);
  const bool odd = (l15 & 1);

  __syncthreads();                              // all waves done reading GEMM LDS
  f16* ep = smem + w * 4864;                    // per-wave 64x76 f16 tile
#pragma unroll
  for (int j = 0; j < 4; ++j) {
    const int d = 16 * j + l15;
    const int p = d >> 1;                        // pair index 0..31
    const float fr = exp2f(-0.8304820237218405f * (float)(p & 15)); // 10000^(-(p%16)/16)
    const bool useY = (p < 16);
    const float bv = bias[n0 + 64 * wc + d];
#pragma unroll
    for (int i = 0; i < 4; ++i) {
      const int nbase = (int)(m0 & 1023) + 64 * wr + 16 * i + qd * 4;
#pragma unroll
      for (int r = 0; r < 4; ++r) {
        const int n = nbase + r;
        float v = acc[i][j][r] + bv;
        if (doRope) {
          const float pv = __shfl_xor(v, 1, 64);   // partner element (d^1)
          const float pos = useY ? (float)(n >> 5) : (float)(n & 31);
          float sn, cn;
          __sincosf(pos * fr, &sn, &cn);
          float res = odd ? (pv * sn + v * cn) : (v * cn - pv * sn);
          if (isQ) res *= 0.18033688011112042f;    // attn scale * log2(e)
          v = res;
        }
        ep[(16 * i + 4 * qd + r) * 76 + d] = (f16)v;
      }
    }
  }
  __syncthreads();                              // LDS writes visible (per-wave suffices)
  // coalesced read-back: 8 rows/iter, 16B/lane, contiguous 1KB per instruction
  const long R0 = (m0 & 1023) + 64 * wr;
  const int cc = (lane & 7) * 8;
#pragma unroll
  for (int it = 0; it < 8; ++it) {
    const int rr = it * 8 + (lane >> 3);
    const uint4 val = *(const uint4*)(ep + rr * 76 + cc);
    *(uint4*)(dstbh + (R0 + rr) * 64 + cc) = val;
  }
}

// ---------------- flash attention: double-buffered K/V LDS, ONE barrier per kt ----------------
__global__ __launch_bounds__(256) void attn_kernel(const f16* __restrict__ Qf, const f16* __restrict__ Kf,
                                                   const f16* __restrict__ Vf, f16* __restrict__ Aout) {
  const int lin = (int)blockIdx.x + ((int)blockIdx.y << 3);   // 0..1535
  const int xcd = lin & 7, idx = lin >> 3;                    // idx 0..191
  const int bh = xcd * 24 + (idx >> 3);                       // bijective remap
  const int qt = idx & 7;
  const int b = bh / 12, h = bh % 12;
  const int tid = threadIdx.x;
  const int lane = tid & 63, w = tid >> 6;
  const int l15 = lane & 15, qd = lane >> 4;

  __shared__ __align__(16) f16 Ks[2][64][72];   // [buf][key][d], rows padded to 72
  __shared__ __align__(16) f16 Vts[2][64][72];  // [buf][d][key] (transposed)
  __shared__ float wsum[128];

  const f16* Qg = Qf + ((long)bh * 1024 + qt * 128) * 64;
  const f16* Kg = Kf + (long)bh * 1024 * 64;
  const f16* Vg = Vf + (long)bh * 1024 * 64;

  half8 qb[2][2];
#pragma unroll
  for (int g = 0; g < 2; ++g)
#pragma unroll
    for (int dc = 0; dc < 2; ++dc)
      qb[g][dc] = *(const half8*)(Qg + (w * 32 + g * 16 + l15) * 64 + dc * 32 + qd * 8);

  float lsum[2] = {0.f, 0.f};
  f32x4 O[2][4];
#pragma unroll
  for (int g = 0; g < 2; ++g)
#pragma unroll
    for (int nt = 0; nt < 4; ++nt) O[g][nt] = (f32x4){0.f, 0.f, 0.f, 0.f};

  const int srow = tid >> 2, sch = (tid & 3) * 16;
  const f16* kgb = Kg + (long)srow * 64 + sch;
  const int sk0 = (tid & 31) * 2, scd = tid >> 5;
  const f16* vgb = Vg + (long)sk0 * 64 + scd * 8;
  uint4 kr0, kr1, vr0, vr1;

  auto writeKV = [&](int buf) {
    *(uint4*)(&Ks[buf][srow][sch])     = kr0;
    *(uint4*)(&Ks[buf][srow][sch + 8]) = kr1;
    union { uint4 u; f16 hh[8]; } ua, ub;
    ua.u = vr0; ub.u = vr1;
#pragma unroll
    for (int i2 = 0; i2 < 8; ++i2) {
      union { u32 u; f16 hh[2]; } t2;
      t2.hh[0] = ua.hh[i2]; t2.hh[1] = ub.hh[i2];
      *(u32*)(&Vts[buf][scd * 8 + i2][sk0]) = t2.u;
    }
  };

  // prologue: tile 0 -> buf0; issue tile 1's loads
  kr0 = *(const uint4*)(kgb);
  kr1 = *(const uint4*)(kgb + 8);
  vr0 = *(const uint4*)(vgb);
  vr1 = *(const uint4*)(vgb + 64);
  writeKV(0);
  kr0 = *(const uint4*)(kgb + 4096);
  kr1 = *(const uint4*)(kgb + 4096 + 8);
  vr0 = *(const uint4*)(vgb + 4096);
  vr1 = *(const uint4*)(vgb + 4096 + 64);
  __syncthreads();

  for (int kt = 0; kt < 16; ++kt) {
    const int cur = kt & 1;
    if (kt < 15) writeKV(cur ^ 1);
    if (kt < 14) {
      const f16* kp = kgb + (kt + 2) * 4096;
      kr0 = *(const uint4*)(kp);
      kr1 = *(const uint4*)(kp + 8);
      const f16* vp = vgb + (kt + 2) * 4096;
      vr0 = *(const uint4*)(vp);
      vr1 = *(const uint4*)(vp + 64);
    }

    f32x4 S[2][4];
#pragma unroll
    for (int kb = 0; kb < 4; ++kb) {
      const half8 ka0 = *(const half8*)(&Ks[cur][kb * 16 + l15][qd * 8]);
      const half8 ka1 = *(const half8*)(&Ks[cur][kb * 16 + l15][32 + qd * 8]);
#pragma unroll
      for (int g = 0; g < 2; ++g) {
        f32x4 z = (f32x4){0.f, 0.f, 0.f, 0.f};
        z = mfma_k32(ka0, qb[g][0], z);
        z = mfma_k32(ka1, qb[g][1], z);
        S[g][kb] = z;
      }
    }

    half8 pa8[2][2];
#pragma unroll
    for (int g = 0; g < 2; ++g)
#pragma unroll
      for (int c = 0; c < 2; ++c) {
        const f32x4 s0 = S[g][2 * c], s1 = S[g][2 * c + 1];
        const float p0 = __builtin_amdgcn_exp2f(s0[0]);
        const float p1 = __builtin_amdgcn_exp2f(s0[1]);
        const float p2 = __builtin_amdgcn_exp2f(s0[2]);
        const float p3 = __builtin_amdgcn_exp2f(s0[3]);
        const float p4 = __builtin_amdgcn_exp2f(s1[0]);
        const float p5 = __builtin_amdgcn_exp2f(s1[1]);
        const float p6 = __builtin_amdgcn_exp2f(s1[2]);
        const float p7 = __builtin_amdgcn_exp2f(s1[3]);
        lsum[g] += ((p0 + p1) + (p2 + p3)) + ((p4 + p5) + (p6 + p7));
        half8 pk;
        pk[0] = (f16)p0; pk[1] = (f16)p1; pk[2] = (f16)p2; pk[3] = (f16)p3;
        pk[4] = (f16)p4; pk[5] = (f16)p5; pk[6] = (f16)p6; pk[7] = (f16)p7;
        pa8[g][c] = pk;
      }

#pragma unroll
    for (int nt = 0; nt < 4; ++nt) {
      half8 vv[2];
#pragma unroll
      for (int c = 0; c < 2; ++c) {
        const half4 v0 = *(const half4*)(&Vts[cur][nt * 16 + l15][c * 32 + qd * 4]);
        const half4 v1 = *(const half4*)(&Vts[cur][nt * 16 + l15][c * 32 + 16 + qd * 4]);
        vv[c] = __builtin_shufflevector(v0, v1, 0, 1, 2, 3, 4, 5, 6, 7);
      }
#pragma unroll
      for (int g = 0; g < 2; ++g) {
        O[g][nt] = mfma_k32(pa8[g][0], vv[0], O[g][nt]);
        O[g][nt] = mfma_k32(pa8[g][1], vv[1], O[g][nt]);
      }
    }
    __syncthreads();   // buf^1 writes visible AND buf reads complete
  }

#pragma unroll
  for (int g = 0; g < 2; ++g) {
    float s = lsum[g];
    s += __shfl_xor(s, 16, 64);
    s += __shfl_xor(s, 32, 64);
    if (lane < 16) wsum[w * 32 + g * 16 + lane] = s;
  }
  __syncthreads();
  float inv[2][4];
#pragma unroll
  for (int g = 0; g < 2; ++g)
#pragma unroll
    for (int r = 0; r < 4; ++r)
      inv[g][r] = 1.f / wsum[w * 32 + g * 16 + qd * 4 + r];
#pragma unroll
  for (int g = 0; g < 2; ++g)
#pragma unroll
    for (int r = 0; r < 4; ++r) {
      const int n = qt * 128 + w * 32 + g * 16 + qd * 4 + r;
      f16* dst = Aout + ((long)b * 1024 + n) * 768 + h * 64;
#pragma unroll
      for (int nt = 0; nt < 4; ++nt)
        dst[nt * 16 + l15] = (f16)(O[g][nt][r] * inv[g][r]);
    }
}

// ---------------- proj GEMM + bias -> f32 out ----------------
__global__ __launch_bounds__(256) void proj_kernel(const f16* __restrict__ A, const f16* __restrict__ W,
                                                   const float* __restrict__ bias, float* __restrict__ out) {
  __shared__ __align__(16) f16 As[12288];   // 3 buf x 128 x 32
  __shared__ __align__(16) f16 Bs[12288];
  f32x4 acc[4][4];
#pragma unroll
  for (int i = 0; i < 4; ++i)
#pragma unroll
    for (int j = 0; j < 4; ++j) acc[i][j] = (f32x4){0.f, 0.f, 0.f, 0.f};
  const long m0 = (long)blockIdx.x * 128;
  const long n0 = (long)blockIdx.y * 128;
  gemm128p(A, W, 768, m0, n0, As, Bs, acc);

  const int tid = threadIdx.x, lane = tid & 63, w = tid >> 6;
  const int l15 = lane & 15, qd = lane >> 4;
  const int wr = w >> 1, wc = w & 1;
#pragma unroll
  for (int j = 0; j < 4; ++j) {
    const int col = (int)n0 + 64 * wc + 16 * j + l15;
    const float bv = bias[col];
#pragma unroll
    for (int i = 0; i < 4; ++i) {
      const long m = m0 + 64 * wr + 16 * i + qd * 4;
#pragma unroll
      for (int r = 0; r < 4; ++r)
        out[(m + r) * 768 + col] = acc[i][j][r] + bv;
    }
  }
}

extern "C" void kernel_launch(void* const* d_in, const int* in_sizes, int n_in,
                              void* d_out, int out_size, void* d_ws, size_t ws_size,
                              hipStream_t stream) {
  const float* x_f    = (const float*)d_in[0];
  const float* qkvw_f = (const float*)d_in[1];
  const float* qkvb_f = (const float*)d_in[2];
  const float* projw_f= (const float*)d_in[3];
  const float* projb_f= (const float*)d_in[4];
  // d_in[5], d_in[6]: height/width = 32 (hardcoded)

  char* ws = (char*)d_ws;
  f16* xh   = (f16*)(ws + 0);           // 16384*768*2  = 25,165,824
  f16* wqh  = (f16*)(ws + 25165824);    // 2304*768*2   =  3,538,944
  f16* wph  = (f16*)(ws + 28704768);    //  768*768*2   =  1,179,648
  f16* Qf   = (f16*)(ws + 29884416);    // 192*1024*64*2 = 25,165,824
  f16* Kf   = (f16*)(ws + 55050240);
  f16* Vf   = (f16*)(ws + 80216064);    // total 105,381,888 B
  f16* Aout = (f16*)(ws + 0);           // aliases xh (dead after qkv_kernel)

  cvt_all_kernel<<<7296, 256, 0, stream>>>(x_f, qkvw_f, projw_f, xh, wqh, wph);
  qkv_kernel<<<dim3(128, 18), 256, 0, stream>>>(xh, wqh, qkvb_f, Qf, Kf, Vf);
  attn_kernel<<<dim3(8, 192), 256, 0, stream>>>(Qf, Kf, Vf, Aout);
  proj_kernel<<<dim3(128, 6), 256, 0, stream>>>(Aout, wph, projb_f, (float*)d_out);
}